// Round 1
// baseline (12.132 us; speedup 1.0000x reference)
//
#include <hip/hip_runtime.h>
#include <math.h>
#include <limits.h>

#define NIMG 32            // 16 set-A images + 16 set-B images
#define NBOX 2000
#define NCLS 81
#define NC (NBOX * NCLS)   // 162000 scores per image
#define NVEC (NC / 4)      // 40500 float4 per image
#define PSPLIT 16          // phase-1 blocks per image
#define THRESH_F 0.05f
#define NEG_INF_F (-1000000000.0f)

__device__ __forceinline__ void comb(float& s, int& i, float s2, int i2) {
    // prefer higher score; on exact tie prefer lower flat index (lax.top_k stability)
    if (s2 > s || (s2 == s && i2 < i)) { s = s2; i = i2; }
}

__global__ __launch_bounds__(256) void phase1_scan(
    const float* __restrict__ clsA, const float* __restrict__ clsB,
    float2* __restrict__ ws)
{
    const int blk  = blockIdx.x;           // 0 .. NIMG*PSPLIT-1
    const int img  = blk / PSPLIT;
    const int part = blk % PSPLIT;
    const float* __restrict__ cls =
        (img < 16) ? (clsA + (size_t)img * NC) : (clsB + (size_t)(img - 16) * NC);

    const int chunk  = (NVEC + PSPLIT - 1) / PSPLIT;   // 2532
    const int vstart = part * chunk;
    const int vend   = min(vstart + chunk, NVEC);

    float best = NEG_INF_F;
    int   bidx = INT_MAX;

    for (int v = vstart + threadIdx.x; v < vend; v += 256) {
        float4 val = reinterpret_cast<const float4*>(cls)[v];
        const int base = v * 4;
        #pragma unroll
        for (int j = 0; j < 4; ++j) {
            float sv = (&val.x)[j];
            int flat = base + j;
            int c = flat % NCLS;
            float sc = (sv > THRESH_F && c != 0) ? sv : NEG_INF_F;
            if (sc > best) { best = sc; bidx = flat; }
            else if (sc == best && flat < bidx) { bidx = flat; }
        }
    }

    // wave64 butterfly reduce
    #pragma unroll
    for (int m = 1; m < 64; m <<= 1) {
        float s2 = __shfl_xor(best, m, 64);
        int   i2 = __shfl_xor(bidx, m, 64);
        comb(best, bidx, s2, i2);
    }

    __shared__ float ss[4];
    __shared__ int   si[4];
    const int wave = threadIdx.x >> 6;
    const int lane = threadIdx.x & 63;
    if (lane == 0) { ss[wave] = best; si[wave] = bidx; }
    __syncthreads();
    if (threadIdx.x == 0) {
        #pragma unroll
        for (int w = 1; w < 4; ++w) comb(best, bidx, ss[w], si[w]);
        ws[img * PSPLIT + part] = make_float2(best, __int_as_float(bidx));
    }
}

__global__ __launch_bounds__(64) void phase2_decode(
    const float2* __restrict__ ws,
    const float* __restrict__ roisA, const float* __restrict__ bbA, const float* __restrict__ imA,
    const float* __restrict__ roisB, const float* __restrict__ bbB, const float* __restrict__ imB,
    float* __restrict__ out)
{
    const int img  = blockIdx.x;
    const int lane = threadIdx.x;

    float best = NEG_INF_F;
    int   bidx = INT_MAX;
    if (lane < PSPLIT) {
        float2 p = ws[img * PSPLIT + lane];
        best = p.x;
        bidx = __float_as_int(p.y);
    }
    #pragma unroll
    for (int m = 1; m < PSPLIT; m <<= 1) {
        float s2 = __shfl_xor(best, m, 64);
        int   i2 = __shfl_xor(bidx, m, 64);
        comb(best, bidx, s2, i2);
    }

    if (lane == 0) {
        const int n = bidx / NCLS;
        const int c = bidx % NCLS;
        const bool isA = (img < 16);
        const int b = isA ? img : (img - 16);
        const float* __restrict__ rois = (isA ? roisA : roisB) + ((size_t)b * NBOX + n) * 4;
        const float* __restrict__ dl   = (isA ? bbA  : bbB ) + ((size_t)b * NBOX + n) * (4 * NCLS) + 4 * c;
        const float* __restrict__ im   = (isA ? imA  : imB ) + (size_t)b * 3;

        const float x1 = rois[0], y1 = rois[1], x2 = rois[2], y2 = rois[3];
        const float w  = x2 - x1 + 1.0f;
        const float h  = y2 - y1 + 1.0f;
        const float cx = x1 + 0.5f * w;
        const float cy = y1 + 0.5f * h;

        const float dx = dl[0], dy = dl[1], dw = dl[2], dh = dl[3];
        const float pcx = dx * w + cx;
        const float pcy = dy * h + cy;
        const float pw  = expf(fminf(fmaxf(dw, -10.0f), 4.0f)) * w;
        const float ph  = expf(fminf(fmaxf(dh, -10.0f), 4.0f)) * h;

        const float H = im[0];
        const float W = im[1];
        const float ox1 = fminf(fmaxf(pcx - 0.5f * pw,        0.0f), W - 1.0f);
        const float oy1 = fminf(fmaxf(pcy - 0.5f * ph,        0.0f), H - 1.0f);
        const float ox2 = fminf(fmaxf(pcx + 0.5f * pw - 1.0f, 0.0f), W - 1.0f);
        const float oy2 = fminf(fmaxf(pcy + 0.5f * ph - 1.0f, 0.0f), H - 1.0f);
        const float sc  = fmaxf(best, 0.0f);

        float* __restrict__ dst = isA ? (out + b * 5) : (out + 80 + b * 5);
        dst[0] = ox1; dst[1] = oy1; dst[2] = ox2; dst[3] = oy2; dst[4] = sc;
        if (isA) out[160 + b] = (float)c;   // sel_id (ids_A[:,0]) as fp32 value
    }
}

extern "C" void kernel_launch(void* const* d_in, const int* in_sizes, int n_in,
                              void* d_out, int out_size, void* d_ws, size_t ws_size,
                              hipStream_t stream) {
    const float* roisA = (const float*)d_in[0];
    const float* clsA  = (const float*)d_in[1];
    const float* bbA   = (const float*)d_in[2];
    const float* imA   = (const float*)d_in[3];
    const float* roisB = (const float*)d_in[4];
    const float* clsB  = (const float*)d_in[5];
    const float* bbB   = (const float*)d_in[6];
    const float* imB   = (const float*)d_in[7];
    float* out = (float*)d_out;
    float2* ws = (float2*)d_ws;   // NIMG*PSPLIT float2 = 4 KiB

    phase1_scan<<<NIMG * PSPLIT, 256, 0, stream>>>(clsA, clsB, ws);
    phase2_decode<<<NIMG, 64, 0, stream>>>(ws, roisA, bbA, imA, roisB, bbB, imB, out);
}